// Round 4
// baseline (1143.956 us; speedup 1.0000x reference)
//
#include <hip/hip_runtime.h>
#include <math.h>

typedef float f4 __attribute__((ext_vector_type(4)));

constexpr int NB  = 8;
constexpr int NN  = 512;
constexpr int NC  = 256;
constexpr int NCQ = 64;
constexpr int NHW = 49;
constexpr int NM  = NB * NN;   // 4096
constexpr int XS  = 260;       // transposed x row stride (floats)

// ---- workspace layout (float offsets) ----
constexpr size_t WS_SMEAN = 0;                        // 8*256            -> 2048
constexpr size_t WS_YST   = 2048;                     // 8*49*256         -> 102400
constexpr size_t WS_UST   = 102400;                   // 8*49*64          -> 127488
constexpr size_t WS_SP    = 127488;                   // 4096             -> 131584
constexpr size_t WS_QMEAN = 131584;                   // 4096*256         -> 1180160
// NMS region aliases QMEAN (strictly after k_fc consumes it)
constexpr size_t WS_SBOX  = WS_QMEAN;                 // 8*512*4
constexpr size_t WS_SAREA = WS_SBOX + 16384;          // 4096
constexpr size_t WS_SIDX  = WS_SAREA + 4096;          // 4096 (ints)
constexpr size_t WS_MASK  = WS_SIDX + 4096;           // 8*512*8 u64 = 65536 floats

// ---- output layout (floats): boxes[4096*4] | scores[4096] | keep[4096] ----
constexpr size_t OUT_SCORES = (size_t)NM * 4;
constexpr size_t OUT_KEEP   = OUT_SCORES + NM;

__device__ __forceinline__ float block_reduce_sum(float v, float* red) {
    int t = threadIdx.x;
#pragma unroll
    for (int off = 32; off > 0; off >>= 1) v += __shfl_down(v, off, 64);
    __syncthreads();
    if ((t & 63) == 0) red[t >> 6] = v;
    __syncthreads();
    return red[0] + red[1] + red[2] + red[3];
}

// stage x [256][49] (global) -> LDS transposed [49][XS] ([hw][c]), b128 writes
__device__ __forceinline__ void stage_xT(const float* __restrict__ g, float* sx, int t) {
#pragma unroll
    for (int rep = 0; rep < 13; ++rep) {
        int id = rep * 256 + t;
        if (id < 3136) {                 // 64 c-quads * 49 hw
            int c4 = id / 49;
            int hw = id - c4 * 49;
            f4 v;
            v[0] = g[(c4 * 4 + 0) * 49 + hw];
            v[1] = g[(c4 * 4 + 1) * 49 + hw];
            v[2] = g[(c4 * 4 + 2) * 49 + hw];
            v[3] = g[(c4 * 4 + 3) * 49 + hw];
            *(f4*)&sx[hw * XS + c4 * 4] = v;
        }
    }
}

// ---------------------------------------------------------------------------
// K1: per-batch precompute. grid = 32 (b*4 + o-quarter), block = 256.
//   smean[b][c]; y_sT[b][hw][o] = (Wcor@x_s); u_sT[b][hw][o2] = (W1s@x_s)
//   Native weight layouts: Wcor[o][c], W1[o2][c] (q: c<256, s: c>=256).
// ---------------------------------------------------------------------------
__global__ __launch_bounds__(256, 2) void k_prep(
    const float* __restrict__ bfs, const float* __restrict__ Wcor,
    const float* __restrict__ W1, float* __restrict__ ws)
{
    __shared__ __align__(16) float smem[49 * XS + 16];
    float* sx = smem;
    int t = threadIdx.x;
    int b = blockIdx.x >> 2;
    int oq = blockIdx.x & 3;

    stage_xT(bfs + (size_t)b * 12544, sx, t);
    __syncthreads();

    if (oq == 0) {
        float s = 0.f;
        for (int hw = 0; hw < 49; ++hw) s += sx[hw * XS + t];
        ws[WS_SMEAN + (size_t)b * 256 + t] = s * (1.f / 49.f);
    }

    int og2 = t >> 3, hwg = t & 7;
    int hwb = (hwg == 7) ? 0 : hwg * 7;
    int oA = oq * 64 + og2 * 2;

    float acc0[7] = {0,0,0,0,0,0,0}, acc1[7] = {0,0,0,0,0,0,0};
    float a1a[7]  = {0,0,0,0,0,0,0}, a1b[7]  = {0,0,0,0,0,0,0};
    const float* xrow = sx + hwb * XS;
    const float* w0r = Wcor + (size_t)oA * 256;
    const float* w1r = Wcor + (size_t)(oA + 1) * 256;
    const float* war = W1 + (size_t)og2 * 512 + 256;        // s-part
    const float* wbr = W1 + (size_t)(og2 + 32) * 512 + 256;

#pragma unroll 1
    for (int c4 = 0; c4 < 64; ++c4) {
        f4 xv[7];
#pragma unroll
        for (int i = 0; i < 7; ++i) xv[i] = *(const f4*)&xrow[i * XS + c4 * 4];
        f4 w0 = *(const f4*)&w0r[c4 * 4];
        f4 w1 = *(const f4*)&w1r[c4 * 4];
        f4 wa = *(const f4*)&war[c4 * 4];
        f4 wb = *(const f4*)&wbr[c4 * 4];
#pragma unroll
        for (int j = 0; j < 4; ++j) {
#pragma unroll
            for (int i = 0; i < 7; ++i) {
                float x = xv[i][j];
                acc0[i] = fmaf(w0[j], x, acc0[i]);
                acc1[i] = fmaf(w1[j], x, acc1[i]);
                a1a[i]  = fmaf(wa[j], x, a1a[i]);
                a1b[i]  = fmaf(wb[j], x, a1b[i]);
            }
        }
    }

    if (hwg < 7) {
#pragma unroll
        for (int i = 0; i < 7; ++i) {
            size_t row = ((size_t)b * 49 + hwb + i);
            ws[WS_YST + row * 256 + oA]     = acc0[i];
            ws[WS_YST + row * 256 + oA + 1] = acc1[i];
            if (oq == 0) {
                ws[WS_UST + row * 64 + og2]      = a1a[i];
                ws[WS_UST + row * 64 + og2 + 32] = a1b[i];
            }
        }
    }
}

// ---------------------------------------------------------------------------
// K2: heavy per-m kernel. grid = 4096, block = 256, 2 blocks/CU.
// Weight loads double-buffered in registers (A/B) to hide L1/L2 latency;
// native [o][c] rows -> 10 f4 loads per c4 (was 16 incl. 8 scalars).
// ---------------------------------------------------------------------------
#define LOADW(P, C4) do {                                   \
    P##0 = *(const f4*)&wc_base[0 * 256 + (C4) * 4];        \
    P##1 = *(const f4*)&wc_base[1 * 256 + (C4) * 4];        \
    P##2 = *(const f4*)&wc_base[2 * 256 + (C4) * 4];        \
    P##3 = *(const f4*)&wc_base[3 * 256 + (C4) * 4];        \
    P##4 = *(const f4*)&wc_base[4 * 256 + (C4) * 4];        \
    P##5 = *(const f4*)&wc_base[5 * 256 + (C4) * 4];        \
    P##6 = *(const f4*)&wc_base[6 * 256 + (C4) * 4];        \
    P##7 = *(const f4*)&wc_base[7 * 256 + (C4) * 4];        \
    P##a = *(const f4*)&wa_base[(C4) * 4];                  \
    P##b = *(const f4*)&wb_base[(C4) * 4];                  \
} while (0)

#define GEMV_STEP(P, C4) do {                               \
    f4 xv[7];                                               \
    _Pragma("unroll")                                       \
    for (int i = 0; i < 7; ++i)                             \
        xv[i] = *(const f4*)&xrow[i * XS + (C4) * 4];       \
    _Pragma("unroll")                                       \
    for (int j = 0; j < 4; ++j) {                           \
        _Pragma("unroll")                                   \
        for (int i = 0; i < 7; ++i) {                       \
            float x = xv[i][j];                             \
            acc[0][i] = fmaf(P##0[j], x, acc[0][i]);        \
            acc[1][i] = fmaf(P##1[j], x, acc[1][i]);        \
            acc[2][i] = fmaf(P##2[j], x, acc[2][i]);        \
            acc[3][i] = fmaf(P##3[j], x, acc[3][i]);        \
            acc[4][i] = fmaf(P##4[j], x, acc[4][i]);        \
            acc[5][i] = fmaf(P##5[j], x, acc[5][i]);        \
            acc[6][i] = fmaf(P##6[j], x, acc[6][i]);        \
            acc[7][i] = fmaf(P##7[j], x, acc[7][i]);        \
            a1a[i]    = fmaf(P##a[j], x, a1a[i]);           \
            a1b[i]    = fmaf(P##b[j], x, a1b[i]);           \
        }                                                   \
    }                                                       \
} while (0)

__global__ __launch_bounds__(256, 2) void k_heavy(
    const float* __restrict__ bfq, const float* __restrict__ Wcor,
    const float* __restrict__ W1,
    const float* __restrict__ W2, const float* __restrict__ W3,
    const float* __restrict__ scor_w, const float* __restrict__ scor_b,
    const float* __restrict__ spr_w, const float* __restrict__ spr_b,
    const float* __restrict__ dpr_w, const float* __restrict__ dpr_b,
    const float* __restrict__ proposals, const int* __restrict__ image_size,
    float* __restrict__ ws, float* __restrict__ out)
{
    __shared__ __align__(16) float smem[49 * XS + 16];   // 51,024 B
    float* sx  = smem;
    float* red = smem + 49 * XS;

    int t = threadIdx.x, m = blockIdx.x, b = m >> 9;

    stage_xT(bfq + (size_t)m * 12544, sx, t);
    __syncthreads();

    // q_mean (thread = channel c, conflict-free LDS column reads)
    {
        float s = 0.f;
        for (int hw = 0; hw < 49; ++hw) s += sx[hw * XS + t];
        ws[WS_QMEAN + (size_t)m * 256 + t] = s * (1.f / 49.f);
    }

    int og = t >> 3, hwg = t & 7;
    int obase = og * 8;
    int hwb = (hwg == 7) ? 0 : hwg * 7;
    const float* xrow = sx + hwb * XS;
    const float* wc_base = Wcor + (size_t)obase * 256;
    const float* wa_base = W1 + (size_t)og * 512;          // q-part row og
    const float* wb_base = W1 + (size_t)(og + 32) * 512;

    float acc[8][7];
#pragma unroll
    for (int oi = 0; oi < 8; ++oi)
#pragma unroll
        for (int i = 0; i < 7; ++i) acc[oi][i] = 0.f;
    float a1a[7] = {0,0,0,0,0,0,0}, a1b[7] = {0,0,0,0,0,0,0};

    f4 A0, A1, A2, A3, A4, A5, A6, A7, Aa, Ab;
    f4 B0, B1, B2, B3, B4, B5, B6, B7, Ba, Bb;

    LOADW(A, 0);
#pragma unroll 1
    for (int c4 = 0; c4 < 62; c4 += 2) {
        LOADW(B, c4 + 1);
        GEMV_STEP(A, c4);
        LOADW(A, c4 + 2);
        GEMV_STEP(B, c4 + 1);
    }
    LOADW(B, 63);
    GEMV_STEP(A, 62);
    GEMV_STEP(B, 63);

    // correlation epilogue: dot z with y_sT, reduce over hw-groups, relu, * scor_w
    float csum = 0.f;
    {
        float corr[8] = {0,0,0,0,0,0,0,0};
        if (hwg < 7) {
#pragma unroll
            for (int i = 0; i < 7; ++i) {
                size_t row = ((size_t)b * 49 + hwb + i);
                f4 y0 = *(const f4*)&ws[WS_YST + row * 256 + obase];
                f4 y1 = *(const f4*)&ws[WS_YST + row * 256 + obase + 4];
                corr[0] = fmaf(acc[0][i], y0[0], corr[0]);
                corr[1] = fmaf(acc[1][i], y0[1], corr[1]);
                corr[2] = fmaf(acc[2][i], y0[2], corr[2]);
                corr[3] = fmaf(acc[3][i], y0[3], corr[3]);
                corr[4] = fmaf(acc[4][i], y1[0], corr[4]);
                corr[5] = fmaf(acc[5][i], y1[1], corr[5]);
                corr[6] = fmaf(acc[6][i], y1[2], corr[6]);
                corr[7] = fmaf(acc[7][i], y1[3], corr[7]);
            }
        }
#pragma unroll
        for (int oi = 0; oi < 8; ++oi) {
            float v = corr[oi];
            v += __shfl_xor(v, 1, 64);
            v += __shfl_xor(v, 2, 64);
            v += __shfl_xor(v, 4, 64);
            corr[oi] = v;
        }
        if (hwg == 0) {
#pragma unroll
            for (int oi = 0; oi < 8; ++oi)
                csum += fmaxf(corr[oi], 0.f) * scor_w[obase + oi];
        }
    }
    __syncthreads();   // all xqT readers done; overlay region free

    // ---- phase 2: x1 -> pool -> conv -> W3 -> pool ----
    float* s1  = sx;                     // [64][52]
    float* sp1 = sx + 64 * 52;           // [64][25]
    float* sc2 = sx + 64 * 52 + 64 * 25; // [64][12]

    if (hwg < 7) {
#pragma unroll
        for (int i = 0; i < 7; ++i) {
            size_t row = ((size_t)b * 49 + hwb + i);
            float u0 = ws[WS_UST + row * 64 + og];
            float u1 = ws[WS_UST + row * 64 + og + 32];
            s1[og * 52 + hwb + i]        = fmaxf(a1a[i] + u0, 0.f);
            s1[(og + 32) * 52 + hwb + i] = fmaxf(a1b[i] + u1, 0.f);
        }
    }
    __syncthreads();

    // avgpool3 7x7 -> 5x5
    for (int i = t; i < 64 * 25; i += 256) {
        int ch = i / 25, pos = i - ch * 25;
        int py = pos / 5, px = pos - py * 5;
        const float* base = s1 + ch * 52 + py * 7 + px;
        float s = base[0] + base[1] + base[2]
                + base[7] + base[8] + base[9]
                + base[14] + base[15] + base[16];
        sp1[ch * 25 + pos] = s * (1.f / 9.f);
    }
    __syncthreads();

    // conv3x3 VALID 64->64 : 5x5 -> 3x3
    for (int i = t; i < 64 * 9; i += 256) {
        int oc = i / 9, pos = i - oc * 9;
        int py = pos / 3, px = pos - py * 3;
        const float* wb = W2 + (size_t)oc * 576;
        float a = 0.f;
        for (int ic = 0; ic < 64; ++ic) {
            const float* pb = sp1 + ic * 25 + py * 5 + px;
            const float* wi = wb + ic * 9;
            a = fmaf(pb[0],  wi[0], a); a = fmaf(pb[1],  wi[1], a); a = fmaf(pb[2],  wi[2], a);
            a = fmaf(pb[5],  wi[3], a); a = fmaf(pb[6],  wi[4], a); a = fmaf(pb[7],  wi[5], a);
            a = fmaf(pb[10], wi[6], a); a = fmaf(pb[11], wi[7], a); a = fmaf(pb[12], wi[8], a);
        }
        sc2[oc * 12 + pos] = fmaxf(a, 0.f);
    }
    __syncthreads();

    // W3 (256x64) + relu + avgpool3 3x3 -> 1
    float xfin;
    {
        float xw[9] = {0,0,0,0,0,0,0,0,0};
        const float* wr = W3 + t * 64;
        for (int ic = 0; ic < 64; ++ic) {
            float w = wr[ic];
            const float* cb = sc2 + ic * 12;
#pragma unroll
            for (int p = 0; p < 9; ++p) xw[p] = fmaf(w, cb[p], xw[p]);
        }
        float s = 0.f;
#pragma unroll
        for (int p = 0; p < 9; ++p) s += fmaxf(xw[p], 0.f);
        xfin = s * (1.f / 9.f);
    }

    float r_s  = block_reduce_sum(xfin * spr_w[t] + csum, red);
    float r_d0 = block_reduce_sum(xfin * dpr_w[0 * 256 + t], red);
    float r_d1 = block_reduce_sum(xfin * dpr_w[1 * 256 + t], red);
    float r_d2 = block_reduce_sum(xfin * dpr_w[2 * 256 + t], red);
    float r_d3 = block_reduce_sum(xfin * dpr_w[3 * 256 + t], red);

    if (t == 0) {
        ws[WS_SP + m] = r_s + spr_b[0] + scor_b[0];

        float d0 = r_d0 + dpr_b[0];
        float d1 = r_d1 + dpr_b[1];
        float d2 = fminf(r_d2 + dpr_b[2], 4.135166556742356f);
        float d3 = fminf(r_d3 + dpr_b[3], 4.135166556742356f);

        const float* pr = proposals + (size_t)m * 4;
        float x1p = pr[0], y1p = pr[1], x2p = pr[2], y2p = pr[3];
        float w  = x2p - x1p, h = y2p - y1p;
        float cx = x1p + 0.5f * w, cy = y1p + 0.5f * h;
        float pcx = d0 * w + cx, pcy = d1 * h + cy;
        float pw = expf(d2) * w, ph = expf(d3) * h;
        float Wf = (float)image_size[1];
        float Hf = (float)image_size[0];
        out[(size_t)m * 4 + 0] = fminf(fmaxf(pcx - 0.5f * pw, 0.f), Wf);
        out[(size_t)m * 4 + 1] = fminf(fmaxf(pcy - 0.5f * ph, 0.f), Hf);
        out[(size_t)m * 4 + 2] = fminf(fmaxf(pcx + 0.5f * pw, 0.f), Wf);
        out[(size_t)m * 4 + 3] = fminf(fmaxf(pcy + 0.5f * ph, 0.f), Hf);
    }
}

// ---------------------------------------------------------------------------
// K3: FC path, 8 m's per block. grid = 512, block = 256.
// ---------------------------------------------------------------------------
__global__ __launch_bounds__(256) void k_fc(
    const float* __restrict__ fc1_w, const float* __restrict__ fc1_b,
    const float* __restrict__ fc2_w, const float* __restrict__ fc2_b,
    const float* __restrict__ sfc_w, const float* __restrict__ sfc_b,
    float* __restrict__ ws, float* __restrict__ out)
{
    __shared__ __align__(16) float sxfc[8][512];
    __shared__ __align__(16) float sh1[8][256];
    __shared__ float s_red[8];
    int t = threadIdx.x;
    int m0 = blockIdx.x * 8;

#pragma unroll
    for (int mi = 0; mi < 8; ++mi) {
        int mg = m0 + mi;
        int b = mg >> 9;
        sxfc[mi][t]       = ws[WS_QMEAN + (size_t)mg * 256 + t];
        sxfc[mi][256 + t] = ws[WS_SMEAN + (size_t)b * 256 + t];
    }
    __syncthreads();

    {
        const f4* wr = (const f4*)(fc1_w + t * 512);
        float acc[8] = {0,0,0,0,0,0,0,0};
        for (int k4 = 0; k4 < 128; ++k4) {
            f4 w = wr[k4];
#pragma unroll
            for (int mi = 0; mi < 8; ++mi) {
                f4 x = ((const f4*)sxfc[mi])[k4];
                acc[mi] = fmaf(w[0], x[0], acc[mi]);
                acc[mi] = fmaf(w[1], x[1], acc[mi]);
                acc[mi] = fmaf(w[2], x[2], acc[mi]);
                acc[mi] = fmaf(w[3], x[3], acc[mi]);
            }
        }
        float bb = fc1_b[t];
#pragma unroll
        for (int mi = 0; mi < 8; ++mi) sh1[mi][t] = fmaxf(acc[mi] + bb, 0.f);
    }
    __syncthreads();

    float val[8];
    {
        const f4* wr = (const f4*)(fc2_w + t * 256);
        float acc[8] = {0,0,0,0,0,0,0,0};
        for (int k4 = 0; k4 < 64; ++k4) {
            f4 w = wr[k4];
#pragma unroll
            for (int mi = 0; mi < 8; ++mi) {
                f4 x = ((const f4*)sh1[mi])[k4];
                acc[mi] = fmaf(w[0], x[0], acc[mi]);
                acc[mi] = fmaf(w[1], x[1], acc[mi]);
                acc[mi] = fmaf(w[2], x[2], acc[mi]);
                acc[mi] = fmaf(w[3], x[3], acc[mi]);
            }
        }
        float bb = fc2_b[t];
        float sw = sfc_w[t];
#pragma unroll
        for (int mi = 0; mi < 8; ++mi) val[mi] = sw * fmaxf(acc[mi] + bb, 0.f);
    }

#pragma unroll
    for (int mi = 0; mi < 8; ++mi) {
        float r = block_reduce_sum(val[mi], s_red);
        if (t == 0) {
            float tot = ws[WS_SP + m0 + mi] + (r + sfc_b[0]);
            out[OUT_SCORES + m0 + mi] = 1.0f / (1.0f + expf(-tot));
        }
    }
}

// ---------------------------------------------------------------------------
// K4: per-batch stable-descending rank sort. grid = 8, block = 256.
// ---------------------------------------------------------------------------
__global__ __launch_bounds__(256) void k_sort(
    const float* __restrict__ out, float* __restrict__ ws)
{
    __shared__ float ssc[512];
    int t = threadIdx.x, b = blockIdx.x;
    const float* sc_g = out + OUT_SCORES + (size_t)b * 512;
    ssc[t] = sc_g[t];
    ssc[t + 256] = sc_g[t + 256];
    __syncthreads();

#pragma unroll
    for (int ii = 0; ii < 2; ++ii) {
        int i = t + ii * 256;
        float si = ssc[i];
        int r = 0;
        for (int j = 0; j < 512; ++j) {
            float sj = ssc[j];
            r += (int)((sj > si) || (sj == si && j < i));
        }
        f4 v = *(const f4*)(out + ((size_t)b * 512 + i) * 4);
        *(f4*)&ws[WS_SBOX + ((size_t)b * 512 + r) * 4] = v;
        ws[WS_SAREA + (size_t)b * 512 + r] =
            fmaxf(v[2] - v[0], 0.f) * fmaxf(v[3] - v[1], 0.f);
        ((int*)ws)[WS_SIDX + (size_t)b * 512 + r] = i;
    }
}

// ---------------------------------------------------------------------------
// K5: IoU bitmask build. grid = 1024, block = 256 (wave per sorted row i).
// ---------------------------------------------------------------------------
__global__ __launch_bounds__(256) void k_mask(float* __restrict__ ws)
{
    int t = threadIdx.x;
    int wv = t >> 6, lane = t & 63;
    int gi = blockIdx.x * 4 + wv;          // 0..4095
    int b = gi >> 9, i = gi & 511;

    f4 bi = *(const f4*)&ws[WS_SBOX + ((size_t)b * 512 + i) * 4];
    float ai = ws[WS_SAREA + (size_t)b * 512 + i];
    unsigned long long* mask = (unsigned long long*)(ws + WS_MASK);

#pragma unroll
    for (int w = 0; w < 8; ++w) {
        int j = w * 64 + lane;
        f4 bj = *(const f4*)&ws[WS_SBOX + ((size_t)b * 512 + j) * 4];
        float aj = ws[WS_SAREA + (size_t)b * 512 + j];
        float xx1 = fmaxf(bi[0], bj[0]), yy1 = fmaxf(bi[1], bj[1]);
        float xx2 = fminf(bi[2], bj[2]), yy2 = fminf(bi[3], bj[3]);
        float inter = fmaxf(xx2 - xx1, 0.f) * fmaxf(yy2 - yy1, 0.f);
        float iou = inter / fmaxf(ai + aj - inter, 1e-9f);
        bool sup = (iou > 0.5f) && (j > i);
        unsigned long long bal = __ballot(sup);
        if (lane == 0) mask[((size_t)b * 512 + i) * 8 + w] = bal;
    }
}

// ---------------------------------------------------------------------------
// K6: sequential greedy pass over bitmasks. grid = 8, block = 64 (1 wave).
// ---------------------------------------------------------------------------
__global__ __launch_bounds__(64) void k_final(
    float* __restrict__ out, const float* __restrict__ wsf)
{
    int lane = threadIdx.x, b = blockIdx.x;
    const unsigned long long* mask =
        (const unsigned long long*)(wsf + WS_MASK) + (size_t)b * 512 * 8;

    unsigned long long kw = ~0ull;                   // lanes 0..7 own words
    unsigned long long nxt = (lane < 8) ? mask[lane] : 0ull;

    for (int i = 0; i < 512; ++i) {
        unsigned long long cur = nxt;
        if (i < 511 && lane < 8) nxt = mask[(size_t)(i + 1) * 8 + lane];
        unsigned long long wi = __shfl(kw, i >> 6, 64);
        if ((wi >> (i & 63)) & 1ull) {
            if (lane < 8) kw &= ~cur;
        }
    }

    const int* sidx = ((const int*)wsf) + WS_SIDX + (size_t)b * 512;
#pragma unroll
    for (int w = 0; w < 8; ++w) {
        unsigned long long word = __shfl(kw, w, 64);
        int r = w * 64 + lane;
        out[OUT_KEEP + (size_t)b * 512 + sidx[r]] =
            ((word >> lane) & 1ull) ? 1.0f : 0.0f;
    }
}

// ---------------------------------------------------------------------------
extern "C" void kernel_launch(void* const* d_in, const int* in_sizes, int n_in,
                              void* d_out, int out_size, void* d_ws, size_t ws_size,
                              hipStream_t stream) {
    const float* bfq       = (const float*)d_in[0];
    const float* bfs       = (const float*)d_in[1];
    const float* proposals = (const float*)d_in[2];
    const int*   image_sz  = (const int*)d_in[3];
    const float* W1        = (const float*)d_in[4];
    const float* W2        = (const float*)d_in[5];
    const float* W3        = (const float*)d_in[6];
    const float* Wcor      = (const float*)d_in[7];
    const float* fc1_w     = (const float*)d_in[8];
    const float* fc1_b     = (const float*)d_in[9];
    const float* fc2_w     = (const float*)d_in[10];
    const float* fc2_b     = (const float*)d_in[11];
    const float* sfc_w     = (const float*)d_in[12];
    const float* sfc_b     = (const float*)d_in[13];
    const float* scor_w    = (const float*)d_in[14];
    const float* scor_b    = (const float*)d_in[15];
    const float* spr_w     = (const float*)d_in[16];
    const float* spr_b     = (const float*)d_in[17];
    const float* dpr_w     = (const float*)d_in[18];
    const float* dpr_b     = (const float*)d_in[19];
    float* out = (float*)d_out;
    float* ws  = (float*)d_ws;

    k_prep<<<32, 256, 0, stream>>>(bfs, Wcor, W1, ws);
    k_heavy<<<NM, 256, 0, stream>>>(bfq, Wcor, W1, W2, W3,
                                    scor_w, scor_b, spr_w, spr_b,
                                    dpr_w, dpr_b, proposals, image_sz, ws, out);
    k_fc<<<NM / 8, 256, 0, stream>>>(fc1_w, fc1_b, fc2_w, fc2_b,
                                     sfc_w, sfc_b, ws, out);
    k_sort<<<NB, 256, 0, stream>>>(out, ws);
    k_mask<<<1024, 256, 0, stream>>>(ws);
    k_final<<<NB, 64, 0, stream>>>(out, ws);
}

// Round 5
// 879.373 us; speedup vs baseline: 1.3009x; 1.3009x over previous
//
#include <hip/hip_runtime.h>
#include <math.h>

typedef float f4 __attribute__((ext_vector_type(4)));
typedef float f32x4 __attribute__((ext_vector_type(4)));
typedef short short8 __attribute__((ext_vector_type(8)));

constexpr int NB  = 8;
constexpr int NN  = 512;
constexpr int NC  = 256;
constexpr int NHW = 49;
constexpr int NM  = NB * NN;   // 4096
constexpr int XS  = 260;       // k_prep transposed x row stride (floats)

// ---- workspace layout (float offsets); total 5.05 MB <= proven >=5.11 MB ----
constexpr size_t WS_SMEAN = 0;                        // 8*256              -> 2048
constexpr size_t WS_YST   = 2048;                     // 8*49*256           -> 102400
constexpr size_t WS_UST   = 102400;                   // 8*49*64            -> 127488
constexpr size_t WS_WFH   = 127488;                   // 20*8*64*8 bf16     -> 168448
constexpr size_t WS_WFL   = 168448;                   // same (lo part)     -> 209408
constexpr size_t WS_SP    = 209408;                   // 4096               -> 213504
constexpr size_t WS_QMEAN = 213504;                   // 4096*256           -> 1262080
// NMS region aliases QMEAN (strictly after k_fc consumes it)
constexpr size_t WS_SBOX  = WS_QMEAN;                 // 8*512*4
constexpr size_t WS_SAREA = WS_SBOX + 16384;          // 4096
constexpr size_t WS_SIDX  = WS_SAREA + 4096;          // 4096 (ints)
constexpr size_t WS_MASK  = WS_SIDX + 4096;           // 8*512 u64x8 = 65536 floats

// ---- output layout (floats): boxes[4096*4] | scores[4096] | keep[4096] ----
constexpr size_t OUT_SCORES = (size_t)NM * 4;
constexpr size_t OUT_KEEP   = OUT_SCORES + NM;

__device__ __forceinline__ float block_reduce_sum(float v, float* red) {
    int t = threadIdx.x;
#pragma unroll
    for (int off = 32; off > 0; off >>= 1) v += __shfl_down(v, off, 64);
    __syncthreads();
    if ((t & 63) == 0) red[t >> 6] = v;
    __syncthreads();
    return red[0] + red[1] + red[2] + red[3];
}

__device__ __forceinline__ unsigned short bf16_rne(float f) {
    unsigned u = __float_as_uint(f);
    return (unsigned short)((u + 0x7FFFu + ((u >> 16) & 1u)) >> 16);
}
__device__ __forceinline__ float bf16_to_f(unsigned short h) {
    return __uint_as_float(((unsigned)h) << 16);
}

// stage x [256][49] (global) -> LDS transposed [49][XS] f32 (k_prep only)
__device__ __forceinline__ void stage_xT(const float* __restrict__ g, float* sx, int t) {
#pragma unroll
    for (int rep = 0; rep < 13; ++rep) {
        int id = rep * 256 + t;
        if (id < 3136) {
            int c4 = id / 49;
            int hw = id - c4 * 49;
            f4 v;
            v[0] = g[(c4 * 4 + 0) * 49 + hw];
            v[1] = g[(c4 * 4 + 1) * 49 + hw];
            v[2] = g[(c4 * 4 + 2) * 49 + hw];
            v[3] = g[(c4 * 4 + 3) * 49 + hw];
            *(f4*)&sx[hw * XS + c4 * 4] = v;
        }
    }
}

// ---------------------------------------------------------------------------
// K0: build split-bf16 A-fragments for W = [Wcor(256); W1q(64)] (320x256).
// grid = 160 (mt*8+ks), block = 64 (one lane each).
// Fragment convention (same one used by the B-side): lane l holds rows
// row = mt*16 + (l&15), k = ks*32 + (l>>4)*8 + j, j=0..7.
// ---------------------------------------------------------------------------
__global__ __launch_bounds__(64) void k_wfrag(
    const float* __restrict__ Wcor, const float* __restrict__ W1,
    float* __restrict__ ws)
{
    int l = threadIdx.x, blk = blockIdx.x;
    int mt = blk >> 3, ks = blk & 7;
    int row = mt * 16 + (l & 15);
    int k0 = ks * 32 + (l >> 4) * 8;
    const float* src = (row < 256) ? (Wcor + (size_t)row * 256 + k0)
                                   : (W1 + (size_t)(row - 256) * 512 + k0);
    short hv[8], lv[8];
#pragma unroll
    for (int j = 0; j < 8; ++j) {
        float v = src[j];
        unsigned short hh = bf16_rne(v);
        unsigned short hl = bf16_rne(v - bf16_to_f(hh));
        hv[j] = (short)hh; lv[j] = (short)hl;
    }
    short* dh = (short*)(ws + WS_WFH) + ((size_t)blk * 64 + l) * 8;
    short* dl = (short*)(ws + WS_WFL) + ((size_t)blk * 64 + l) * 8;
#pragma unroll
    for (int j = 0; j < 8; ++j) { dh[j] = hv[j]; dl[j] = lv[j]; }
}

// ---------------------------------------------------------------------------
// K1: per-batch precompute (f32 exact). grid = 32 (b*4 + o-quarter), block=256.
//   smean[b][c]; y_sT[b][hw][o] = Wcor@x_s; u_sT[b][hw][o2] = W1s@x_s
// ---------------------------------------------------------------------------
__global__ __launch_bounds__(256, 2) void k_prep(
    const float* __restrict__ bfs, const float* __restrict__ Wcor,
    const float* __restrict__ W1, float* __restrict__ ws)
{
    __shared__ __align__(16) float smem[49 * XS + 16];
    float* sx = smem;
    int t = threadIdx.x;
    int b = blockIdx.x >> 2;
    int oq = blockIdx.x & 3;

    stage_xT(bfs + (size_t)b * 12544, sx, t);
    __syncthreads();

    if (oq == 0) {
        float s = 0.f;
        for (int hw = 0; hw < 49; ++hw) s += sx[hw * XS + t];
        ws[WS_SMEAN + (size_t)b * 256 + t] = s * (1.f / 49.f);
    }

    int og2 = t >> 3, hwg = t & 7;
    int hwb = (hwg == 7) ? 0 : hwg * 7;
    int oA = oq * 64 + og2 * 2;

    float acc0[7] = {0,0,0,0,0,0,0}, acc1[7] = {0,0,0,0,0,0,0};
    float a1a[7]  = {0,0,0,0,0,0,0}, a1b[7]  = {0,0,0,0,0,0,0};
    const float* xrow = sx + hwb * XS;
    const float* w0r = Wcor + (size_t)oA * 256;
    const float* w1r = Wcor + (size_t)(oA + 1) * 256;
    const float* war = W1 + (size_t)og2 * 512 + 256;
    const float* wbr = W1 + (size_t)(og2 + 32) * 512 + 256;

#pragma unroll 1
    for (int c4 = 0; c4 < 64; ++c4) {
        f4 xv[7];
#pragma unroll
        for (int i = 0; i < 7; ++i) xv[i] = *(const f4*)&xrow[i * XS + c4 * 4];
        f4 w0 = *(const f4*)&w0r[c4 * 4];
        f4 w1 = *(const f4*)&w1r[c4 * 4];
        f4 wa = *(const f4*)&war[c4 * 4];
        f4 wb = *(const f4*)&wbr[c4 * 4];
#pragma unroll
        for (int j = 0; j < 4; ++j) {
#pragma unroll
            for (int i = 0; i < 7; ++i) {
                float x = xv[i][j];
                acc0[i] = fmaf(w0[j], x, acc0[i]);
                acc1[i] = fmaf(w1[j], x, acc1[i]);
                a1a[i]  = fmaf(wa[j], x, a1a[i]);
                a1b[i]  = fmaf(wb[j], x, a1b[i]);
            }
        }
    }

    if (hwg < 7) {
#pragma unroll
        for (int i = 0; i < 7; ++i) {
            size_t row = ((size_t)b * 49 + hwb + i);
            ws[WS_YST + row * 256 + oA]     = acc0[i];
            ws[WS_YST + row * 256 + oA + 1] = acc1[i];
            if (oq == 0) {
                ws[WS_UST + row * 64 + og2]      = a1a[i];
                ws[WS_UST + row * 64 + og2 + 32] = a1b[i];
            }
        }
    }
}

// ---------------------------------------------------------------------------
// K2: heavy per-m kernel, MFMA split-bf16. grid = 4096, block = 256 (4 waves).
// Wave w owns M-tiles {w, w+4, w+8, w+12, w+16}; acc = 5x4 f32x4 (80 VGPR).
// B (x) staged in LDS as xT[hw(64)][c(256)] bf16 hi/lo, XOR-swizzled (T2).
// 3 passes HH, HL, LH accumulate into the same acc.
// ---------------------------------------------------------------------------
__global__ __launch_bounds__(256, 2) void k_heavy(
    const float* __restrict__ bfq,
    const float* __restrict__ W2, const float* __restrict__ W3,
    const float* __restrict__ scor_w, const float* __restrict__ scor_b,
    const float* __restrict__ spr_w, const float* __restrict__ spr_b,
    const float* __restrict__ dpr_w, const float* __restrict__ dpr_b,
    const float* __restrict__ proposals, const int* __restrict__ image_size,
    float* __restrict__ ws, float* __restrict__ out)
{
    __shared__ __align__(16) short xb[2][64 * 256];   // 64 KiB (hi, lo)
    __shared__ float red[8];

    int t = threadIdx.x, m = blockIdx.x, b = m >> 9;

    // ---- stage x -> bf16 hi/lo (swizzled), q_mean ----
    {
        const float* xg = bfq + (size_t)m * 12544 + (size_t)t * 49;
        float qs = 0.f;
#pragma unroll 1
        for (int hw = 0; hw < 49; ++hw) {
            float v = xg[hw];
            qs += v;
            unsigned short hh = bf16_rne(v);
            unsigned short hl = bf16_rne(v - bf16_to_f(hh));
            int idx = (hw * 256 + t) ^ ((hw & 7) << 3);
            xb[0][idx] = (short)hh;
            xb[1][idx] = (short)hl;
        }
        ws[WS_QMEAN + (size_t)m * 256 + t] = qs * (1.f / 49.f);
    }
    __syncthreads();

    int w = t >> 6, l = t & 63, cl = l & 15, g = l >> 4;

    f32x4 acc[5][4];
#pragma unroll
    for (int i = 0; i < 5; ++i)
#pragma unroll
        for (int nt = 0; nt < 4; ++nt) acc[i][nt] = (f32x4)0.f;

    const short* wfH = (const short*)(ws + WS_WFH);
    const short* wfL = (const short*)(ws + WS_WFL);

#pragma unroll 1
    for (int pass = 0; pass < 3; ++pass) {
        const short* af = (pass == 2) ? wfL : wfH;
        const short* bsrc = (pass == 1) ? xb[1] : xb[0];
#pragma unroll 1
        for (int ks = 0; ks < 8; ++ks) {
            short8 bfr[4];
#pragma unroll
            for (int nt = 0; nt < 4; ++nt) {
                int col = nt * 16 + cl;
                int idx = (col * 256 + ks * 32 + g * 8) ^ ((col & 7) << 3);
                bfr[nt] = *(const short8*)&bsrc[idx];
            }
#pragma unroll
            for (int i = 0; i < 5; ++i) {
                int mt = w + 4 * i;
                short8 a = *(const short8*)&af[((size_t)(mt * 8 + ks) * 64 + l) * 8];
                acc[i][0] = __builtin_amdgcn_mfma_f32_16x16x32_bf16(a, bfr[0], acc[i][0], 0, 0, 0);
                acc[i][1] = __builtin_amdgcn_mfma_f32_16x16x32_bf16(a, bfr[1], acc[i][1], 0, 0, 0);
                acc[i][2] = __builtin_amdgcn_mfma_f32_16x16x32_bf16(a, bfr[2], acc[i][2], 0, 0, 0);
                acc[i][3] = __builtin_amdgcn_mfma_f32_16x16x32_bf16(a, bfr[3], acc[i][3], 0, 0, 0);
            }
        }
    }

    // ---- corr epilogue: tiles w,w+4,w+8,w+12 are Wcor rows (<256).
    // C/D layout (m89): col = lane&15, row_in_tile = (lane>>4)*4 + reg.
    float csum = 0.f;
    {
        const float* yb = ws + WS_YST + (size_t)b * 49 * 256;
#pragma unroll
        for (int i = 0; i < 4; ++i) {
            int row0 = (w + 4 * i) * 16 + g * 4;
#pragma unroll
            for (int q = 0; q < 4; ++q) {
                int row = row0 + q;
                float p = 0.f;
#pragma unroll
                for (int nt = 0; nt < 4; ++nt) {
                    int col = nt * 16 + cl;
                    if (col < 49) p += acc[i][nt][q] * yb[(size_t)col * 256 + row];
                }
                p += __shfl_xor(p, 1, 64);
                p += __shfl_xor(p, 2, 64);
                p += __shfl_xor(p, 4, 64);
                p += __shfl_xor(p, 8, 64);
                if (cl == 0) csum += fmaxf(p, 0.f) * scor_w[row];
            }
        }
    }
    __syncthreads();   // ALL waves done with MFMA B-reads; xb reusable

    // ---- x1 epilogue: tile w+16 = W1q rows; write s1[64][52] over xb ----
    float* s1  = (float*)xb;
    float* sp1 = s1 + 64 * 52;
    float* sc2 = s1 + 64 * 52 + 64 * 25;
    {
        const float* ub = ws + WS_UST + (size_t)b * 49 * 64;
        int ch0 = w * 16 + g * 4;
#pragma unroll
        for (int q = 0; q < 4; ++q) {
            int ch = ch0 + q;
#pragma unroll
            for (int nt = 0; nt < 4; ++nt) {
                int col = nt * 16 + cl;
                if (col < 49)
                    s1[ch * 52 + col] = fmaxf(acc[4][nt][q] + ub[(size_t)col * 64 + ch], 0.f);
            }
        }
    }
    __syncthreads();

    // ---- phase 2: pool -> conv -> W3 -> pool (f32 vector, as round 3) ----
    for (int i = t; i < 64 * 25; i += 256) {
        int ch = i / 25, pos = i - ch * 25;
        int py = pos / 5, px = pos - py * 5;
        const float* base = s1 + ch * 52 + py * 7 + px;
        float s = base[0] + base[1] + base[2]
                + base[7] + base[8] + base[9]
                + base[14] + base[15] + base[16];
        sp1[ch * 25 + pos] = s * (1.f / 9.f);
    }
    __syncthreads();

    for (int i = t; i < 64 * 9; i += 256) {
        int oc = i / 9, pos = i - oc * 9;
        int py = pos / 3, px = pos - py * 3;
        const float* wb = W2 + (size_t)oc * 576;
        float a = 0.f;
        for (int ic = 0; ic < 64; ++ic) {
            const float* pb = sp1 + ic * 25 + py * 5 + px;
            const float* wi = wb + ic * 9;
            a = fmaf(pb[0],  wi[0], a); a = fmaf(pb[1],  wi[1], a); a = fmaf(pb[2],  wi[2], a);
            a = fmaf(pb[5],  wi[3], a); a = fmaf(pb[6],  wi[4], a); a = fmaf(pb[7],  wi[5], a);
            a = fmaf(pb[10], wi[6], a); a = fmaf(pb[11], wi[7], a); a = fmaf(pb[12], wi[8], a);
        }
        sc2[oc * 12 + pos] = fmaxf(a, 0.f);
    }
    __syncthreads();

    float xfin;
    {
        float xw[9] = {0,0,0,0,0,0,0,0,0};
        const float* wr = W3 + t * 64;
        for (int ic = 0; ic < 64; ++ic) {
            float wv = wr[ic];
            const float* cb = sc2 + ic * 12;
#pragma unroll
            for (int p = 0; p < 9; ++p) xw[p] = fmaf(wv, cb[p], xw[p]);
        }
        float s = 0.f;
#pragma unroll
        for (int p = 0; p < 9; ++p) s += fmaxf(xw[p], 0.f);
        xfin = s * (1.f / 9.f);
    }

    float r_s  = block_reduce_sum(xfin * spr_w[t] + csum, red);
    float r_d0 = block_reduce_sum(xfin * dpr_w[0 * 256 + t], red);
    float r_d1 = block_reduce_sum(xfin * dpr_w[1 * 256 + t], red);
    float r_d2 = block_reduce_sum(xfin * dpr_w[2 * 256 + t], red);
    float r_d3 = block_reduce_sum(xfin * dpr_w[3 * 256 + t], red);

    if (t == 0) {
        ws[WS_SP + m] = r_s + spr_b[0] + scor_b[0];

        float d0 = r_d0 + dpr_b[0];
        float d1 = r_d1 + dpr_b[1];
        float d2 = fminf(r_d2 + dpr_b[2], 4.135166556742356f);
        float d3 = fminf(r_d3 + dpr_b[3], 4.135166556742356f);

        const float* pr = proposals + (size_t)m * 4;
        float x1p = pr[0], y1p = pr[1], x2p = pr[2], y2p = pr[3];
        float wd = x2p - x1p, hd = y2p - y1p;
        float cx = x1p + 0.5f * wd, cy = y1p + 0.5f * hd;
        float pcx = d0 * wd + cx, pcy = d1 * hd + cy;
        float pw = expf(d2) * wd, ph = expf(d3) * hd;
        float Wf = (float)image_size[1];
        float Hf = (float)image_size[0];
        out[(size_t)m * 4 + 0] = fminf(fmaxf(pcx - 0.5f * pw, 0.f), Wf);
        out[(size_t)m * 4 + 1] = fminf(fmaxf(pcy - 0.5f * ph, 0.f), Hf);
        out[(size_t)m * 4 + 2] = fminf(fmaxf(pcx + 0.5f * pw, 0.f), Wf);
        out[(size_t)m * 4 + 3] = fminf(fmaxf(pcy + 0.5f * ph, 0.f), Hf);
    }
}

// ---------------------------------------------------------------------------
// K3: FC path, 8 m's per block. grid = 512, block = 256.
// ---------------------------------------------------------------------------
__global__ __launch_bounds__(256) void k_fc(
    const float* __restrict__ fc1_w, const float* __restrict__ fc1_b,
    const float* __restrict__ fc2_w, const float* __restrict__ fc2_b,
    const float* __restrict__ sfc_w, const float* __restrict__ sfc_b,
    float* __restrict__ ws, float* __restrict__ out)
{
    __shared__ __align__(16) float sxfc[8][512];
    __shared__ __align__(16) float sh1[8][256];
    __shared__ float s_red[8];
    int t = threadIdx.x;
    int m0 = blockIdx.x * 8;

#pragma unroll
    for (int mi = 0; mi < 8; ++mi) {
        int mg = m0 + mi;
        int b = mg >> 9;
        sxfc[mi][t]       = ws[WS_QMEAN + (size_t)mg * 256 + t];
        sxfc[mi][256 + t] = ws[WS_SMEAN + (size_t)b * 256 + t];
    }
    __syncthreads();

    {
        const f4* wr = (const f4*)(fc1_w + t * 512);
        float acc[8] = {0,0,0,0,0,0,0,0};
        for (int k4 = 0; k4 < 128; ++k4) {
            f4 w = wr[k4];
#pragma unroll
            for (int mi = 0; mi < 8; ++mi) {
                f4 x = ((const f4*)sxfc[mi])[k4];
                acc[mi] = fmaf(w[0], x[0], acc[mi]);
                acc[mi] = fmaf(w[1], x[1], acc[mi]);
                acc[mi] = fmaf(w[2], x[2], acc[mi]);
                acc[mi] = fmaf(w[3], x[3], acc[mi]);
            }
        }
        float bb = fc1_b[t];
#pragma unroll
        for (int mi = 0; mi < 8; ++mi) sh1[mi][t] = fmaxf(acc[mi] + bb, 0.f);
    }
    __syncthreads();

    float val[8];
    {
        const f4* wr = (const f4*)(fc2_w + t * 256);
        float acc[8] = {0,0,0,0,0,0,0,0};
        for (int k4 = 0; k4 < 64; ++k4) {
            f4 w = wr[k4];
#pragma unroll
            for (int mi = 0; mi < 8; ++mi) {
                f4 x = ((const f4*)sh1[mi])[k4];
                acc[mi] = fmaf(w[0], x[0], acc[mi]);
                acc[mi] = fmaf(w[1], x[1], acc[mi]);
                acc[mi] = fmaf(w[2], x[2], acc[mi]);
                acc[mi] = fmaf(w[3], x[3], acc[mi]);
            }
        }
        float bb = fc2_b[t];
        float sw = sfc_w[t];
#pragma unroll
        for (int mi = 0; mi < 8; ++mi) val[mi] = sw * fmaxf(acc[mi] + bb, 0.f);
    }

#pragma unroll
    for (int mi = 0; mi < 8; ++mi) {
        float r = block_reduce_sum(val[mi], s_red);
        if (t == 0) {
            float tot = ws[WS_SP + m0 + mi] + (r + sfc_b[0]);
            out[OUT_SCORES + m0 + mi] = 1.0f / (1.0f + expf(-tot));
        }
    }
}

// ---------------------------------------------------------------------------
// K4: per-batch stable-descending rank sort. grid = 8, block = 256.
// ---------------------------------------------------------------------------
__global__ __launch_bounds__(256) void k_sort(
    const float* __restrict__ out, float* __restrict__ ws)
{
    __shared__ float ssc[512];
    int t = threadIdx.x, b = blockIdx.x;
    const float* sc_g = out + OUT_SCORES + (size_t)b * 512;
    ssc[t] = sc_g[t];
    ssc[t + 256] = sc_g[t + 256];
    __syncthreads();

#pragma unroll
    for (int ii = 0; ii < 2; ++ii) {
        int i = t + ii * 256;
        float si = ssc[i];
        int r = 0;
        for (int j = 0; j < 512; ++j) {
            float sj = ssc[j];
            r += (int)((sj > si) || (sj == si && j < i));
        }
        f4 v = *(const f4*)(out + ((size_t)b * 512 + i) * 4);
        *(f4*)&ws[WS_SBOX + ((size_t)b * 512 + r) * 4] = v;
        ws[WS_SAREA + (size_t)b * 512 + r] =
            fmaxf(v[2] - v[0], 0.f) * fmaxf(v[3] - v[1], 0.f);
        ((int*)ws)[WS_SIDX + (size_t)b * 512 + r] = i;
    }
}

// ---------------------------------------------------------------------------
// K5: IoU bitmask build. grid = 1024, block = 256 (wave per sorted row i).
// ---------------------------------------------------------------------------
__global__ __launch_bounds__(256) void k_mask(float* __restrict__ ws)
{
    int t = threadIdx.x;
    int wv = t >> 6, lane = t & 63;
    int gi = blockIdx.x * 4 + wv;
    int b = gi >> 9, i = gi & 511;

    f4 bi = *(const f4*)&ws[WS_SBOX + ((size_t)b * 512 + i) * 4];
    float ai = ws[WS_SAREA + (size_t)b * 512 + i];
    unsigned long long* mask = (unsigned long long*)(ws + WS_MASK);

#pragma unroll
    for (int w = 0; w < 8; ++w) {
        int j = w * 64 + lane;
        f4 bj = *(const f4*)&ws[WS_SBOX + ((size_t)b * 512 + j) * 4];
        float aj = ws[WS_SAREA + (size_t)b * 512 + j];
        float xx1 = fmaxf(bi[0], bj[0]), yy1 = fmaxf(bi[1], bj[1]);
        float xx2 = fminf(bi[2], bj[2]), yy2 = fminf(bi[3], bj[3]);
        float inter = fmaxf(xx2 - xx1, 0.f) * fmaxf(yy2 - yy1, 0.f);
        float iou = inter / fmaxf(ai + aj - inter, 1e-9f);
        bool sup = (iou > 0.5f) && (j > i);
        unsigned long long bal = __ballot(sup);
        if (lane == 0) mask[((size_t)b * 512 + i) * 8 + w] = bal;
    }
}

// ---------------------------------------------------------------------------
// K6: sequential greedy pass over bitmasks. grid = 8, block = 64 (1 wave).
// ---------------------------------------------------------------------------
__global__ __launch_bounds__(64) void k_final(
    float* __restrict__ out, const float* __restrict__ wsf)
{
    int lane = threadIdx.x, b = blockIdx.x;
    const unsigned long long* mask =
        (const unsigned long long*)(wsf + WS_MASK) + (size_t)b * 512 * 8;

    unsigned long long kw = ~0ull;
    unsigned long long nxt = (lane < 8) ? mask[lane] : 0ull;

    for (int i = 0; i < 512; ++i) {
        unsigned long long cur = nxt;
        if (i < 511 && lane < 8) nxt = mask[(size_t)(i + 1) * 8 + lane];
        unsigned long long wi = __shfl(kw, i >> 6, 64);
        if ((wi >> (i & 63)) & 1ull) {
            if (lane < 8) kw &= ~cur;
        }
    }

    const int* sidx = ((const int*)wsf) + WS_SIDX + (size_t)b * 512;
#pragma unroll
    for (int w = 0; w < 8; ++w) {
        unsigned long long word = __shfl(kw, w, 64);
        int r = w * 64 + lane;
        out[OUT_KEEP + (size_t)b * 512 + sidx[r]] =
            ((word >> lane) & 1ull) ? 1.0f : 0.0f;
    }
}

// ---------------------------------------------------------------------------
extern "C" void kernel_launch(void* const* d_in, const int* in_sizes, int n_in,
                              void* d_out, int out_size, void* d_ws, size_t ws_size,
                              hipStream_t stream) {
    const float* bfq       = (const float*)d_in[0];
    const float* bfs       = (const float*)d_in[1];
    const float* proposals = (const float*)d_in[2];
    const int*   image_sz  = (const int*)d_in[3];
    const float* W1        = (const float*)d_in[4];
    const float* W2        = (const float*)d_in[5];
    const float* W3        = (const float*)d_in[6];
    const float* Wcor      = (const float*)d_in[7];
    const float* fc1_w     = (const float*)d_in[8];
    const float* fc1_b     = (const float*)d_in[9];
    const float* fc2_w     = (const float*)d_in[10];
    const float* fc2_b     = (const float*)d_in[11];
    const float* sfc_w     = (const float*)d_in[12];
    const float* sfc_b     = (const float*)d_in[13];
    const float* scor_w    = (const float*)d_in[14];
    const float* scor_b    = (const float*)d_in[15];
    const float* spr_w     = (const float*)d_in[16];
    const float* spr_b     = (const float*)d_in[17];
    const float* dpr_w     = (const float*)d_in[18];
    const float* dpr_b     = (const float*)d_in[19];
    float* out = (float*)d_out;
    float* ws  = (float*)d_ws;

    k_wfrag<<<160, 64, 0, stream>>>(Wcor, W1, ws);
    k_prep<<<32, 256, 0, stream>>>(bfs, Wcor, W1, ws);
    k_heavy<<<NM, 256, 0, stream>>>(bfq, W2, W3,
                                    scor_w, scor_b, spr_w, spr_b,
                                    dpr_w, dpr_b, proposals, image_sz, ws, out);
    k_fc<<<NM / 8, 256, 0, stream>>>(fc1_w, fc1_b, fc2_w, fc2_b,
                                     sfc_w, sfc_b, ws, out);
    k_sort<<<NB, 256, 0, stream>>>(out, ws);
    k_mask<<<1024, 256, 0, stream>>>(ws);
    k_final<<<NB, 64, 0, stream>>>(out, ws);
}

// Round 6
// 673.480 us; speedup vs baseline: 1.6986x; 1.3057x over previous
//
#include <hip/hip_runtime.h>
#include <math.h>

typedef float f4 __attribute__((ext_vector_type(4)));
typedef f4 f4u __attribute__((aligned(4)));   // 4B-aligned vector load
typedef float f32x4 __attribute__((ext_vector_type(4)));
typedef short short8 __attribute__((ext_vector_type(8)));

constexpr int NB  = 8;
constexpr int NN  = 512;
constexpr int NC  = 256;
constexpr int NHW = 49;
constexpr int NM  = NB * NN;   // 4096
constexpr int XS  = 260;       // k_prep transposed x row stride (floats)

// ---- workspace layout (float offsets) ----
constexpr size_t WS_SMEAN = 0;                        // 8*256              -> 2048
constexpr size_t WS_YST   = 2048;                     // 8*256*49           -> 102400
constexpr size_t WS_UST   = 102400;                   // 8*64*49            -> 127488
constexpr size_t WS_WFH   = 127488;                   // 20*8*64*8 bf16     -> 168448
constexpr size_t WS_WFL   = 168448;                   // same (lo part)     -> 209408
constexpr size_t WS_SP    = 209408;                   // 4096               -> 213504
constexpr size_t WS_QMEAN = 213504;                   // 4096*256           -> 1262080
// NMS region aliases QMEAN (strictly after k_fc consumes it)
constexpr size_t WS_SBOX  = WS_QMEAN;                 // 8*512*4
constexpr size_t WS_SAREA = WS_SBOX + 16384;          // 4096
constexpr size_t WS_SIDX  = WS_SAREA + 4096;          // 4096 (ints)
constexpr size_t WS_MASK  = WS_SIDX + 4096;           // 8*512 u64x8 = 65536 floats

// ---- output layout (floats): boxes[4096*4] | scores[4096] | keep[4096] ----
constexpr size_t OUT_SCORES = (size_t)NM * 4;
constexpr size_t OUT_KEEP   = OUT_SCORES + NM;

__device__ __forceinline__ float block_reduce_sum(float v, float* red) {
    int t = threadIdx.x;
#pragma unroll
    for (int off = 32; off > 0; off >>= 1) v += __shfl_down(v, off, 64);
    __syncthreads();
    if ((t & 63) == 0) red[t >> 6] = v;
    __syncthreads();
    return red[0] + red[1] + red[2] + red[3];
}

__device__ __forceinline__ unsigned short bf16_rne(float f) {
    unsigned u = __float_as_uint(f);
    return (unsigned short)((u + 0x7FFFu + ((u >> 16) & 1u)) >> 16);
}
__device__ __forceinline__ float bf16_to_f(unsigned short h) {
    return __uint_as_float(((unsigned)h) << 16);
}

// stage x [256][49] (global) -> LDS transposed [49][XS] f32 (k_prep only)
__device__ __forceinline__ void stage_xT(const float* __restrict__ g, float* sx, int t) {
#pragma unroll
    for (int rep = 0; rep < 13; ++rep) {
        int id = rep * 256 + t;
        if (id < 3136) {
            int c4 = id / 49;
            int hw = id - c4 * 49;
            f4 v;
            v[0] = g[(c4 * 4 + 0) * 49 + hw];
            v[1] = g[(c4 * 4 + 1) * 49 + hw];
            v[2] = g[(c4 * 4 + 2) * 49 + hw];
            v[3] = g[(c4 * 4 + 3) * 49 + hw];
            *(f4*)&sx[hw * XS + c4 * 4] = v;
        }
    }
}

// ---------------------------------------------------------------------------
// K0: build split-bf16 A-fragments for W = [Wcor(256); W1q(64)] (320x256).
// grid = 160 (mt*8+ks), block = 64. Lane l holds rows row = mt*16 + (l&15),
// k = ks*32 + (l>>4)*8 + j  (convention HW-verified in round 5: absmax 0).
// ---------------------------------------------------------------------------
__global__ __launch_bounds__(64) void k_wfrag(
    const float* __restrict__ Wcor, const float* __restrict__ W1,
    float* __restrict__ ws)
{
    int l = threadIdx.x, blk = blockIdx.x;
    int mt = blk >> 3, ks = blk & 7;
    int row = mt * 16 + (l & 15);
    int k0 = ks * 32 + (l >> 4) * 8;
    const float* src = (row < 256) ? (Wcor + (size_t)row * 256 + k0)
                                   : (W1 + (size_t)(row - 256) * 512 + k0);
    short hv[8], lv[8];
#pragma unroll
    for (int j = 0; j < 8; ++j) {
        float v = src[j];
        unsigned short hh = bf16_rne(v);
        unsigned short hl = bf16_rne(v - bf16_to_f(hh));
        hv[j] = (short)hh; lv[j] = (short)hl;
    }
    short* dh = (short*)(ws + WS_WFH) + ((size_t)blk * 64 + l) * 8;
    short* dl = (short*)(ws + WS_WFL) + ((size_t)blk * 64 + l) * 8;
#pragma unroll
    for (int j = 0; j < 8; ++j) { dh[j] = hv[j]; dl[j] = lv[j]; }
}

// ---------------------------------------------------------------------------
// K1: per-batch precompute (f32 exact). grid = 32 (b*4 + o-quarter), block=256.
//   smean[b][c]; y_s[b][o][hw] = Wcor@x_s; u_s[b][o2][hw] = W1s@x_s
//   (o-major layout so k_heavy epilogue reads are hw-contiguous / coalesced)
// ---------------------------------------------------------------------------
__global__ __launch_bounds__(256, 2) void k_prep(
    const float* __restrict__ bfs, const float* __restrict__ Wcor,
    const float* __restrict__ W1, float* __restrict__ ws)
{
    __shared__ __align__(16) float smem[49 * XS + 16];
    float* sx = smem;
    int t = threadIdx.x;
    int b = blockIdx.x >> 2;
    int oq = blockIdx.x & 3;

    stage_xT(bfs + (size_t)b * 12544, sx, t);
    __syncthreads();

    if (oq == 0) {
        float s = 0.f;
        for (int hw = 0; hw < 49; ++hw) s += sx[hw * XS + t];
        ws[WS_SMEAN + (size_t)b * 256 + t] = s * (1.f / 49.f);
    }

    int og2 = t >> 3, hwg = t & 7;
    int hwb = (hwg == 7) ? 0 : hwg * 7;
    int oA = oq * 64 + og2 * 2;

    float acc0[7] = {0,0,0,0,0,0,0}, acc1[7] = {0,0,0,0,0,0,0};
    float a1a[7]  = {0,0,0,0,0,0,0}, a1b[7]  = {0,0,0,0,0,0,0};
    const float* xrow = sx + hwb * XS;
    const float* w0r = Wcor + (size_t)oA * 256;
    const float* w1r = Wcor + (size_t)(oA + 1) * 256;
    const float* war = W1 + (size_t)og2 * 512 + 256;
    const float* wbr = W1 + (size_t)(og2 + 32) * 512 + 256;

#pragma unroll 1
    for (int c4 = 0; c4 < 64; ++c4) {
        f4 xv[7];
#pragma unroll
        for (int i = 0; i < 7; ++i) xv[i] = *(const f4*)&xrow[i * XS + c4 * 4];
        f4 w0 = *(const f4*)&w0r[c4 * 4];
        f4 w1 = *(const f4*)&w1r[c4 * 4];
        f4 wa = *(const f4*)&war[c4 * 4];
        f4 wb = *(const f4*)&wbr[c4 * 4];
#pragma unroll
        for (int j = 0; j < 4; ++j) {
#pragma unroll
            for (int i = 0; i < 7; ++i) {
                float x = xv[i][j];
                acc0[i] = fmaf(w0[j], x, acc0[i]);
                acc1[i] = fmaf(w1[j], x, acc1[i]);
                a1a[i]  = fmaf(wa[j], x, a1a[i]);
                a1b[i]  = fmaf(wb[j], x, a1b[i]);
            }
        }
    }

    if (hwg < 7) {
#pragma unroll
        for (int i = 0; i < 7; ++i) {
            int hw = hwb + i;
            ws[WS_YST + ((size_t)b * 256 + oA)     * 49 + hw] = acc0[i];
            ws[WS_YST + ((size_t)b * 256 + oA + 1) * 49 + hw] = acc1[i];
            if (oq == 0) {
                ws[WS_UST + ((size_t)b * 64 + og2)      * 49 + hw] = a1a[i];
                ws[WS_UST + ((size_t)b * 64 + og2 + 32) * 49 + hw] = a1b[i];
            }
        }
    }
}

// ---------------------------------------------------------------------------
// K2: heavy per-m kernel, MFMA split-bf16, 3 passes time-multiplexing ONE
// 32 KB LDS x-buffer: HH, LH on x_hi -> barrier -> restage x_lo -> HL.
// grid = 4096, block = 256 (4 waves), 4 blocks/CU (33 KB LDS, VGPR<=128).
// ---------------------------------------------------------------------------
__global__ __launch_bounds__(256, 4) void k_heavy(
    const float* __restrict__ bfq,
    const float* __restrict__ W2, const float* __restrict__ W3,
    const float* __restrict__ scor_w, const float* __restrict__ scor_b,
    const float* __restrict__ spr_w, const float* __restrict__ spr_b,
    const float* __restrict__ dpr_w, const float* __restrict__ dpr_b,
    const float* __restrict__ proposals, const int* __restrict__ image_size,
    float* __restrict__ ws, float* __restrict__ out)
{
    __shared__ __align__(16) short xb[64 * 256];   // 32 KiB, time-multiplexed
    __shared__ float red[8];

    int t = threadIdx.x, m = blockIdx.x, b = m >> 9;
    const float* xg = bfq + (size_t)m * 12544 + (size_t)t * 49;

    // ---- stage x_hi (f4 vector reads), q_mean ----
    {
        float qs = 0.f;
#pragma unroll 1
        for (int r = 0; r < 12; ++r) {
            f4u v = *(const f4u*)&xg[r * 4];
#pragma unroll
            for (int j = 0; j < 4; ++j) {
                int hw = r * 4 + j;
                float x = v[j];
                qs += x;
                xb[(hw * 256 + t) ^ ((hw & 7) << 3)] = (short)bf16_rne(x);
            }
        }
        float x48 = xg[48];
        qs += x48;
        xb[48 * 256 + t] = (short)bf16_rne(x48);   // 48&7 == 0 -> no xor
        ws[WS_QMEAN + (size_t)m * 256 + t] = qs * (1.f / 49.f);
    }
    __syncthreads();

    int w = t >> 6, l = t & 63, cl = l & 15, g = l >> 4;

    f32x4 acc[5][4];
#pragma unroll
    for (int i = 0; i < 5; ++i)
#pragma unroll
        for (int nt = 0; nt < 4; ++nt) acc[i][nt] = (f32x4)0.f;

    const short* wfH = (const short*)(ws + WS_WFH);
    const short* wfL = (const short*)(ws + WS_WFL);

    auto do_pass = [&](const short* af) {
#pragma unroll 1
        for (int ks = 0; ks < 8; ++ks) {
            short8 bfr[4];
#pragma unroll
            for (int nt = 0; nt < 4; ++nt) {
                int col = nt * 16 + cl;
                int idx = (col * 256 + ks * 32 + g * 8) ^ ((col & 7) << 3);
                bfr[nt] = *(const short8*)&xb[idx];
            }
#pragma unroll
            for (int i = 0; i < 5; ++i) {
                int mt = w + 4 * i;
                short8 a = *(const short8*)&af[((size_t)(mt * 8 + ks) * 64 + l) * 8];
                acc[i][0] = __builtin_amdgcn_mfma_f32_16x16x32_bf16(a, bfr[0], acc[i][0], 0, 0, 0);
                acc[i][1] = __builtin_amdgcn_mfma_f32_16x16x32_bf16(a, bfr[1], acc[i][1], 0, 0, 0);
                acc[i][2] = __builtin_amdgcn_mfma_f32_16x16x32_bf16(a, bfr[2], acc[i][2], 0, 0, 0);
                acc[i][3] = __builtin_amdgcn_mfma_f32_16x16x32_bf16(a, bfr[3], acc[i][3], 0, 0, 0);
            }
        }
    };

    do_pass(wfH);            // HH
    do_pass(wfL);            // LH
    __syncthreads();         // all waves done reading x_hi

    // ---- restage x_lo into the same buffer ----
    {
#pragma unroll 1
        for (int r = 0; r < 12; ++r) {
            f4u v = *(const f4u*)&xg[r * 4];
#pragma unroll
            for (int j = 0; j < 4; ++j) {
                int hw = r * 4 + j;
                float x = v[j];
                unsigned short hh = bf16_rne(x);
                xb[(hw * 256 + t) ^ ((hw & 7) << 3)] =
                    (short)bf16_rne(x - bf16_to_f(hh));
            }
        }
        float x48 = xg[48];
        unsigned short hh = bf16_rne(x48);
        xb[48 * 256 + t] = (short)bf16_rne(x48 - bf16_to_f(hh));
    }
    __syncthreads();

    do_pass(wfH);            // HL

    // ---- corr epilogue: tiles w,w+4,w+8,w+12 = Wcor rows (<256).
    // C/D layout (m89): col = lane&15, row_in_tile = (lane>>4)*4 + reg.
    // y_s[b][o][hw] o-major -> reads are hw-contiguous.
    float csum = 0.f;
    {
        const float* yb = ws + WS_YST + (size_t)b * 256 * 49;
#pragma unroll
        for (int i = 0; i < 4; ++i) {
            int row0 = (w + 4 * i) * 16 + g * 4;
#pragma unroll
            for (int q = 0; q < 4; ++q) {
                int row = row0 + q;
                float p = 0.f;
#pragma unroll
                for (int nt = 0; nt < 4; ++nt) {
                    int col = nt * 16 + cl;
                    if (col < 49) p += acc[i][nt][q] * yb[(size_t)row * 49 + col];
                }
                p += __shfl_xor(p, 1, 64);
                p += __shfl_xor(p, 2, 64);
                p += __shfl_xor(p, 4, 64);
                p += __shfl_xor(p, 8, 64);
                if (cl == 0) csum += fmaxf(p, 0.f) * scor_w[row];
            }
        }
    }
    __syncthreads();   // ALL waves done with MFMA B-reads; xb reusable

    // ---- x1 epilogue: tile w+16 = W1q rows; write s1[64][52] over xb ----
    float* s1  = (float*)xb;                 // [64][52]  13312 B
    float* sp1 = s1 + 64 * 52;               // [64][25]
    float* sc2 = s1 + 64 * 52 + 64 * 25;     // [64][12]  total 22.7 KB < 32 KB
    {
        const float* ub = ws + WS_UST + (size_t)b * 64 * 49;
        int ch0 = w * 16 + g * 4;
#pragma unroll
        for (int q = 0; q < 4; ++q) {
            int ch = ch0 + q;
#pragma unroll
            for (int nt = 0; nt < 4; ++nt) {
                int col = nt * 16 + cl;
                if (col < 49)
                    s1[ch * 52 + col] = fmaxf(acc[4][nt][q] + ub[(size_t)ch * 49 + col], 0.f);
            }
        }
    }
    __syncthreads();

    // ---- phase 2: pool -> conv -> W3 -> pool (f32 vector) ----
    for (int i = t; i < 64 * 25; i += 256) {
        int ch = i / 25, pos = i - ch * 25;
        int py = pos / 5, px = pos - py * 5;
        const float* base = s1 + ch * 52 + py * 7 + px;
        float s = base[0] + base[1] + base[2]
                + base[7] + base[8] + base[9]
                + base[14] + base[15] + base[16];
        sp1[ch * 25 + pos] = s * (1.f / 9.f);
    }
    __syncthreads();

    for (int i = t; i < 64 * 9; i += 256) {
        int oc = i / 9, pos = i - oc * 9;
        int py = pos / 3, px = pos - py * 3;
        const float* wb = W2 + (size_t)oc * 576;
        float a = 0.f;
        for (int ic = 0; ic < 64; ++ic) {
            const float* pb = sp1 + ic * 25 + py * 5 + px;
            const float* wi = wb + ic * 9;
            a = fmaf(pb[0],  wi[0], a); a = fmaf(pb[1],  wi[1], a); a = fmaf(pb[2],  wi[2], a);
            a = fmaf(pb[5],  wi[3], a); a = fmaf(pb[6],  wi[4], a); a = fmaf(pb[7],  wi[5], a);
            a = fmaf(pb[10], wi[6], a); a = fmaf(pb[11], wi[7], a); a = fmaf(pb[12], wi[8], a);
        }
        sc2[oc * 12 + pos] = fmaxf(a, 0.f);
    }
    __syncthreads();

    float xfin;
    {
        float xw[9] = {0,0,0,0,0,0,0,0,0};
        const float* wr = W3 + t * 64;
        for (int ic = 0; ic < 64; ++ic) {
            float wv = wr[ic];
            const float* cb = sc2 + ic * 12;
#pragma unroll
            for (int p = 0; p < 9; ++p) xw[p] = fmaf(wv, cb[p], xw[p]);
        }
        float s = 0.f;
#pragma unroll
        for (int p = 0; p < 9; ++p) s += fmaxf(xw[p], 0.f);
        xfin = s * (1.f / 9.f);
    }

    float r_s  = block_reduce_sum(xfin * spr_w[t] + csum, red);
    float r_d0 = block_reduce_sum(xfin * dpr_w[0 * 256 + t], red);
    float r_d1 = block_reduce_sum(xfin * dpr_w[1 * 256 + t], red);
    float r_d2 = block_reduce_sum(xfin * dpr_w[2 * 256 + t], red);
    float r_d3 = block_reduce_sum(xfin * dpr_w[3 * 256 + t], red);

    if (t == 0) {
        ws[WS_SP + m] = r_s + spr_b[0] + scor_b[0];

        float d0 = r_d0 + dpr_b[0];
        float d1 = r_d1 + dpr_b[1];
        float d2 = fminf(r_d2 + dpr_b[2], 4.135166556742356f);
        float d3 = fminf(r_d3 + dpr_b[3], 4.135166556742356f);

        const float* pr = proposals + (size_t)m * 4;
        float x1p = pr[0], y1p = pr[1], x2p = pr[2], y2p = pr[3];
        float wd = x2p - x1p, hd = y2p - y1p;
        float cx = x1p + 0.5f * wd, cy = y1p + 0.5f * hd;
        float pcx = d0 * wd + cx, pcy = d1 * hd + cy;
        float pw = expf(d2) * wd, ph = expf(d3) * hd;
        float Wf = (float)image_size[1];
        float Hf = (float)image_size[0];
        out[(size_t)m * 4 + 0] = fminf(fmaxf(pcx - 0.5f * pw, 0.f), Wf);
        out[(size_t)m * 4 + 1] = fminf(fmaxf(pcy - 0.5f * ph, 0.f), Hf);
        out[(size_t)m * 4 + 2] = fminf(fmaxf(pcx + 0.5f * pw, 0.f), Wf);
        out[(size_t)m * 4 + 3] = fminf(fmaxf(pcy + 0.5f * ph, 0.f), Hf);
    }
}

// ---------------------------------------------------------------------------
// K3: FC path, 8 m's per block. grid = 512, block = 256.
// ---------------------------------------------------------------------------
__global__ __launch_bounds__(256) void k_fc(
    const float* __restrict__ fc1_w, const float* __restrict__ fc1_b,
    const float* __restrict__ fc2_w, const float* __restrict__ fc2_b,
    const float* __restrict__ sfc_w, const float* __restrict__ sfc_b,
    float* __restrict__ ws, float* __restrict__ out)
{
    __shared__ __align__(16) float sxfc[8][512];
    __shared__ __align__(16) float sh1[8][256];
    __shared__ float s_red[8];
    int t = threadIdx.x;
    int m0 = blockIdx.x * 8;

#pragma unroll
    for (int mi = 0; mi < 8; ++mi) {
        int mg = m0 + mi;
        int b = mg >> 9;
        sxfc[mi][t]       = ws[WS_QMEAN + (size_t)mg * 256 + t];
        sxfc[mi][256 + t] = ws[WS_SMEAN + (size_t)b * 256 + t];
    }
    __syncthreads();

    {
        const f4* wr = (const f4*)(fc1_w + t * 512);
        float acc[8] = {0,0,0,0,0,0,0,0};
        for (int k4 = 0; k4 < 128; ++k4) {
            f4 w = wr[k4];
#pragma unroll
            for (int mi = 0; mi < 8; ++mi) {
                f4 x = ((const f4*)sxfc[mi])[k4];
                acc[mi] = fmaf(w[0], x[0], acc[mi]);
                acc[mi] = fmaf(w[1], x[1], acc[mi]);
                acc[mi] = fmaf(w[2], x[2], acc[mi]);
                acc[mi] = fmaf(w[3], x[3], acc[mi]);
            }
        }
        float bb = fc1_b[t];
#pragma unroll
        for (int mi = 0; mi < 8; ++mi) sh1[mi][t] = fmaxf(acc[mi] + bb, 0.f);
    }
    __syncthreads();

    float val[8];
    {
        const f4* wr = (const f4*)(fc2_w + t * 256);
        float acc[8] = {0,0,0,0,0,0,0,0};
        for (int k4 = 0; k4 < 64; ++k4) {
            f4 w = wr[k4];
#pragma unroll
            for (int mi = 0; mi < 8; ++mi) {
                f4 x = ((const f4*)sh1[mi])[k4];
                acc[mi] = fmaf(w[0], x[0], acc[mi]);
                acc[mi] = fmaf(w[1], x[1], acc[mi]);
                acc[mi] = fmaf(w[2], x[2], acc[mi]);
                acc[mi] = fmaf(w[3], x[3], acc[mi]);
            }
        }
        float bb = fc2_b[t];
        float sw = sfc_w[t];
#pragma unroll
        for (int mi = 0; mi < 8; ++mi) val[mi] = sw * fmaxf(acc[mi] + bb, 0.f);
    }

#pragma unroll
    for (int mi = 0; mi < 8; ++mi) {
        float r = block_reduce_sum(val[mi], s_red);
        if (t == 0) {
            float tot = ws[WS_SP + m0 + mi] + (r + sfc_b[0]);
            out[OUT_SCORES + m0 + mi] = 1.0f / (1.0f + expf(-tot));
        }
    }
}

// ---------------------------------------------------------------------------
// K4: per-batch stable-descending rank sort. grid = 8, block = 256.
// ---------------------------------------------------------------------------
__global__ __launch_bounds__(256) void k_sort(
    const float* __restrict__ out, float* __restrict__ ws)
{
    __shared__ float ssc[512];
    int t = threadIdx.x, b = blockIdx.x;
    const float* sc_g = out + OUT_SCORES + (size_t)b * 512;
    ssc[t] = sc_g[t];
    ssc[t + 256] = sc_g[t + 256];
    __syncthreads();

#pragma unroll
    for (int ii = 0; ii < 2; ++ii) {
        int i = t + ii * 256;
        float si = ssc[i];
        int r = 0;
        for (int j = 0; j < 512; ++j) {
            float sj = ssc[j];
            r += (int)((sj > si) || (sj == si && j < i));
        }
        f4 v = *(const f4*)(out + ((size_t)b * 512 + i) * 4);
        *(f4*)&ws[WS_SBOX + ((size_t)b * 512 + r) * 4] = v;
        ws[WS_SAREA + (size_t)b * 512 + r] =
            fmaxf(v[2] - v[0], 0.f) * fmaxf(v[3] - v[1], 0.f);
        ((int*)ws)[WS_SIDX + (size_t)b * 512 + r] = i;
    }
}

// ---------------------------------------------------------------------------
// K5: IoU bitmask build. grid = 1024, block = 256 (wave per sorted row i).
// ---------------------------------------------------------------------------
__global__ __launch_bounds__(256) void k_mask(float* __restrict__ ws)
{
    int t = threadIdx.x;
    int wv = t >> 6, lane = t & 63;
    int gi = blockIdx.x * 4 + wv;
    int b = gi >> 9, i = gi & 511;

    f4 bi = *(const f4*)&ws[WS_SBOX + ((size_t)b * 512 + i) * 4];
    float ai = ws[WS_SAREA + (size_t)b * 512 + i];
    unsigned long long* mask = (unsigned long long*)(ws + WS_MASK);

#pragma unroll
    for (int w = 0; w < 8; ++w) {
        int j = w * 64 + lane;
        f4 bj = *(const f4*)&ws[WS_SBOX + ((size_t)b * 512 + j) * 4];
        float aj = ws[WS_SAREA + (size_t)b * 512 + j];
        float xx1 = fmaxf(bi[0], bj[0]), yy1 = fmaxf(bi[1], bj[1]);
        float xx2 = fminf(bi[2], bj[2]), yy2 = fminf(bi[3], bj[3]);
        float inter = fmaxf(xx2 - xx1, 0.f) * fmaxf(yy2 - yy1, 0.f);
        float iou = inter / fmaxf(ai + aj - inter, 1e-9f);
        bool sup = (iou > 0.5f) && (j > i);
        unsigned long long bal = __ballot(sup);
        if (lane == 0) mask[((size_t)b * 512 + i) * 8 + w] = bal;
    }
}

// ---------------------------------------------------------------------------
// K6: sequential greedy pass over bitmasks. grid = 8, block = 64 (1 wave).
// ---------------------------------------------------------------------------
__global__ __launch_bounds__(64) void k_final(
    float* __restrict__ out, const float* __restrict__ wsf)
{
    int lane = threadIdx.x, b = blockIdx.x;
    const unsigned long long* mask =
        (const unsigned long long*)(wsf + WS_MASK) + (size_t)b * 512 * 8;

    unsigned long long kw = ~0ull;
    unsigned long long nxt = (lane < 8) ? mask[lane] : 0ull;

    for (int i = 0; i < 512; ++i) {
        unsigned long long cur = nxt;
        if (i < 511 && lane < 8) nxt = mask[(size_t)(i + 1) * 8 + lane];
        unsigned long long wi = __shfl(kw, i >> 6, 64);
        if ((wi >> (i & 63)) & 1ull) {
            if (lane < 8) kw &= ~cur;
        }
    }

    const int* sidx = ((const int*)wsf) + WS_SIDX + (size_t)b * 512;
#pragma unroll
    for (int w = 0; w < 8; ++w) {
        unsigned long long word = __shfl(kw, w, 64);
        int r = w * 64 + lane;
        out[OUT_KEEP + (size_t)b * 512 + sidx[r]] =
            ((word >> lane) & 1ull) ? 1.0f : 0.0f;
    }
}

// ---------------------------------------------------------------------------
extern "C" void kernel_launch(void* const* d_in, const int* in_sizes, int n_in,
                              void* d_out, int out_size, void* d_ws, size_t ws_size,
                              hipStream_t stream) {
    const float* bfq       = (const float*)d_in[0];
    const float* bfs       = (const float*)d_in[1];
    const float* proposals = (const float*)d_in[2];
    const int*   image_sz  = (const int*)d_in[3];
    const float* W1        = (const float*)d_in[4];
    const float* W2        = (const float*)d_in[5];
    const float* W3        = (const float*)d_in[6];
    const float* Wcor      = (const float*)d_in[7];
    const float* fc1_w     = (const float*)d_in[8];
    const float* fc1_b     = (const float*)d_in[9];
    const float* fc2_w     = (const float*)d_in[10];
    const float* fc2_b     = (const float*)d_in[11];
    const float* sfc_w     = (const float*)d_in[12];
    const float* sfc_b     = (const float*)d_in[13];
    const float* scor_w    = (const float*)d_in[14];
    const float* scor_b    = (const float*)d_in[15];
    const float* spr_w     = (const float*)d_in[16];
    const float* spr_b     = (const float*)d_in[17];
    const float* dpr_w     = (const float*)d_in[18];
    const float* dpr_b     = (const float*)d_in[19];
    float* out = (float*)d_out;
    float* ws  = (float*)d_ws;

    k_wfrag<<<160, 64, 0, stream>>>(Wcor, W1, ws);
    k_prep<<<32, 256, 0, stream>>>(bfs, Wcor, W1, ws);
    k_heavy<<<NM, 256, 0, stream>>>(bfq, W2, W3,
                                    scor_w, scor_b, spr_w, spr_b,
                                    dpr_w, dpr_b, proposals, image_sz, ws, out);
    k_fc<<<NM / 8, 256, 0, stream>>>(fc1_w, fc1_b, fc2_w, fc2_b,
                                     sfc_w, sfc_b, ws, out);
    k_sort<<<NB, 256, 0, stream>>>(out, ws);
    k_mask<<<1024, 256, 0, stream>>>(ws);
    k_final<<<NB, 64, 0, stream>>>(out, ws);
}